// Round 1
// baseline (1166.400 us; speedup 1.0000x reference)
//
#include <hip/hip_runtime.h>

#define HID 64
#define HEADS 4
#define TPB 256
#define PTS 16

// ---------------------------------------------------------------------------
// K1: logits[b][h][n] = sc_b2[h] + sum_d relu(sc_b1[h,d] + sum_f pw[f]*sc_w1[h,f,d]) * sc_w2[h,d]
// lane-per-point; weights packed in LDS as [h][d][{w1 f0..5, b1, w2}] -> broadcast reads.
// ---------------------------------------------------------------------------
__global__ __launch_bounds__(TPB) void k_logits(
    const float* __restrict__ rxy, const float* __restrict__ rdir,
    const float* __restrict__ pts,
    const float* __restrict__ sw1, const float* __restrict__ sb1,
    const float* __restrict__ sw2, const float* __restrict__ sb2,
    float* __restrict__ logits, int N)
{
    __shared__ float pk[HEADS * HID * 8];
    const int tid = threadIdx.x;
    for (int idx = tid; idx < HEADS * HID; idx += TPB) {
        const int h = idx >> 6, d = idx & 63;
#pragma unroll
        for (int f = 0; f < 6; ++f) pk[idx * 8 + f] = sw1[(h * 6 + f) * HID + d];
        pk[idx * 8 + 6] = sb1[idx];
        pk[idx * 8 + 7] = sw2[idx];
    }
    __syncthreads();

    const int b = blockIdx.y;
    const float rx = rxy[2 * b], ry = rxy[2 * b + 1];
    const float dx = rdir[2 * b], dy = rdir[2 * b + 1];
    const float2* __restrict__ p2 = reinterpret_cast<const float2*>(pts) + (size_t)b * N;
    float* __restrict__ lg = logits + (size_t)b * HEADS * N;
    const int base = blockIdx.x * (TPB * PTS);
    const float b20 = sb2[0], b21 = sb2[1], b22 = sb2[2], b23 = sb2[3];
    const float4* __restrict__ pk4 = reinterpret_cast<const float4*>(pk);

    for (int i = 0; i < PTS; ++i) {
        const int n = base + i * TPB + tid;
        const int nc = (n < N) ? n : (N - 1);
        const float2 p = p2[nc];
        float acc[HEADS];
#pragma unroll
        for (int h = 0; h < HEADS; ++h) {
            float a = 0.f;
            const float4* wh = pk4 + h * HID * 2;
#pragma unroll 8
            for (int d = 0; d < HID; ++d) {
                const float4 wa = wh[2 * d];
                const float4 wb = wh[2 * d + 1];
                float s = wb.z;
                s = fmaf(rx, wa.x, s); s = fmaf(ry, wa.y, s);
                s = fmaf(dx, wa.z, s); s = fmaf(dy, wa.w, s);
                s = fmaf(p.x, wb.x, s); s = fmaf(p.y, wb.y, s);
                a = fmaf(fmaxf(s, 0.f), wb.w, a);
            }
            acc[h] = a;
        }
        if (n < N) {
            lg[0 * (size_t)N + n] = acc[0] + b20;
            lg[1 * (size_t)N + n] = acc[1] + b21;
            lg[2 * (size_t)N + n] = acc[2] + b22;
            lg[3 * (size_t)N + n] = acc[3] + b23;
        }
    }
}

// ---------------------------------------------------------------------------
// K2: per (b,h): M = max_n logit, S = sum exp(logit - M); store {M, 1/S}
// ---------------------------------------------------------------------------
__global__ __launch_bounds__(TPB) void k_stats(
    const float* __restrict__ logits, float* __restrict__ stats, int N)
{
    const int bh = blockIdx.x;
    const float* __restrict__ lg = logits + (size_t)bh * N;
    const int tid = threadIdx.x;

    float m = -1e30f;
    for (int n = tid; n < N; n += TPB) m = fmaxf(m, lg[n]);
#pragma unroll
    for (int off = 32; off; off >>= 1) m = fmaxf(m, __shfl_xor(m, off));
    __shared__ float sm[4];
    const int w = tid >> 6;
    if ((tid & 63) == 0) sm[w] = m;
    __syncthreads();
    m = fmaxf(fmaxf(sm[0], sm[1]), fmaxf(sm[2], sm[3]));

    float s = 0.f;
    for (int n = tid; n < N; n += TPB) s += __expf(lg[n] - m);
#pragma unroll
    for (int off = 32; off; off >>= 1) s += __shfl_xor(s, off);
    __shared__ float ss[4];
    if ((tid & 63) == 0) ss[w] = s;
    __syncthreads();
    if (tid == 0) {
        const float tot = ss[0] + ss[1] + ss[2] + ss[3];
        stats[bh * 2 + 0] = m;
        stats[bh * 2 + 1] = 1.0f / tot;
    }
}

// ---------------------------------------------------------------------------
// K3: point features + softmax-weighted pooling.
// lane-per-point: h1[64] in regs; per d: pf_d from broadcast LDS w2t reads,
// butterfly-reduce w_h*pf_d over the wave's 64 points; lane d keeps ctx[h][d].
// ---------------------------------------------------------------------------
__global__ __launch_bounds__(TPB) void k_ctx(
    const float* __restrict__ rxy, const float* __restrict__ rdir,
    const float* __restrict__ pts,
    const float* __restrict__ ew1, const float* __restrict__ eb1,
    const float* __restrict__ ew2, const float* __restrict__ eb2,
    const float* __restrict__ logits, const float* __restrict__ stats,
    float* __restrict__ gctx, int N)
{
    __shared__ float w2t[HID * HID];   // w2t[d*64+k] = ew2[k*64+d]
    __shared__ float pk[HID * 8];      // [k][{w1 f0..5, b1, b2}]
    const int tid = threadIdx.x;
    for (int idx = tid; idx < HID * HID; idx += TPB)
        w2t[idx] = ew2[(idx & 63) * HID + (idx >> 6)];
    for (int idx = tid; idx < HID; idx += TPB) {
#pragma unroll
        for (int f = 0; f < 6; ++f) pk[idx * 8 + f] = ew1[f * HID + idx];
        pk[idx * 8 + 6] = eb1[idx];
        pk[idx * 8 + 7] = eb2[idx];
    }
    __syncthreads();

    const int b = blockIdx.y;
    const float rx = rxy[2 * b], ry = rxy[2 * b + 1];
    const float dxx = rdir[2 * b], dyy = rdir[2 * b + 1];
    const float M0 = stats[(b * 4 + 0) * 2], i0 = stats[(b * 4 + 0) * 2 + 1];
    const float M1 = stats[(b * 4 + 1) * 2], i1 = stats[(b * 4 + 1) * 2 + 1];
    const float M2 = stats[(b * 4 + 2) * 2], i2 = stats[(b * 4 + 2) * 2 + 1];
    const float M3 = stats[(b * 4 + 3) * 2], i3 = stats[(b * 4 + 3) * 2 + 1];
    const int lane = tid & 63;
    const float2* __restrict__ p2 = reinterpret_cast<const float2*>(pts) + (size_t)b * N;
    const float* __restrict__ lg = logits + (size_t)b * HEADS * N;
    const int base = blockIdx.x * (TPB * PTS);
    const float4* __restrict__ pk4 = reinterpret_cast<const float4*>(pk);
    const float4* __restrict__ wt4 = reinterpret_cast<const float4*>(w2t);

    float cx0 = 0.f, cx1 = 0.f, cx2 = 0.f, cx3 = 0.f;

    for (int i = 0; i < PTS; ++i) {
        const int n = base + i * TPB + tid;
        const int nc = (n < N) ? n : (N - 1);
        const float2 p = p2[nc];
        const float valid = (n < N) ? 1.f : 0.f;
        const float w0 = __expf(lg[0 * (size_t)N + nc] - M0) * i0 * valid;
        const float w1 = __expf(lg[1 * (size_t)N + nc] - M1) * i1 * valid;
        const float w2 = __expf(lg[2 * (size_t)N + nc] - M2) * i2 * valid;
        const float w3 = __expf(lg[3 * (size_t)N + nc] - M3) * i3 * valid;

        float h1[HID];
#pragma unroll
        for (int k = 0; k < HID; ++k) {
            const float4 wa = pk4[2 * k];
            const float4 wb = pk4[2 * k + 1];
            float s = wb.z;
            s = fmaf(rx, wa.x, s); s = fmaf(ry, wa.y, s);
            s = fmaf(dxx, wa.z, s); s = fmaf(dyy, wa.w, s);
            s = fmaf(p.x, wb.x, s); s = fmaf(p.y, wb.y, s);
            h1[k] = fmaxf(s, 0.f);
        }

        for (int d = 0; d < HID; ++d) {
            float pf = pk[d * 8 + 7];  // enc_b2[d]
#pragma unroll
            for (int kk = 0; kk < HID / 4; ++kk) {
                const float4 wv = wt4[d * 16 + kk];
                pf = fmaf(h1[4 * kk + 0], wv.x, pf);
                pf = fmaf(h1[4 * kk + 1], wv.y, pf);
                pf = fmaf(h1[4 * kk + 2], wv.z, pf);
                pf = fmaf(h1[4 * kk + 3], wv.w, pf);
            }
            float c0 = w0 * pf, c1 = w1 * pf, c2 = w2 * pf, c3 = w3 * pf;
#pragma unroll
            for (int off = 32; off; off >>= 1) {
                c0 += __shfl_xor(c0, off);
                c1 += __shfl_xor(c1, off);
                c2 += __shfl_xor(c2, off);
                c3 += __shfl_xor(c3, off);
            }
            if (lane == d) { cx0 += c0; cx1 += c1; cx2 += c2; cx3 += c3; }
        }
    }

    atomicAdd(&gctx[b * 256 + 0 * HID + lane], cx0);
    atomicAdd(&gctx[b * 256 + 1 * HID + lane], cx1);
    atomicAdd(&gctx[b * 256 + 2 * HID + lane], cx2);
    atomicAdd(&gctx[b * 256 + 3 * HID + lane], cx3);
}

// ---------------------------------------------------------------------------
// K4: out[b] = relu(fc @ out_w1 + out_b1) @ out_w2 + out_b2, fc = gctx[b][:]
// one wave per batch row; lane = output hidden dim.
// ---------------------------------------------------------------------------
__global__ __launch_bounds__(64) void k_out(
    const float* __restrict__ gctx,
    const float* __restrict__ ow1, const float* __restrict__ ob1,
    const float* __restrict__ ow2, const float* __restrict__ ob2,
    float* __restrict__ out)
{
    const int b = blockIdx.x;
    const int lane = threadIdx.x;
    __shared__ float fc[HEADS * HID];
#pragma unroll
    for (int i = 0; i < 4; ++i) fc[lane + 64 * i] = gctx[b * 256 + lane + 64 * i];
    __syncthreads();

    float o = ob1[lane];
#pragma unroll 8
    for (int k = 0; k < HEADS * HID; ++k)
        o = fmaf(fc[k], ow1[k * 64 + lane], o);
    o = fmaxf(o, 0.f) * ow2[lane];
#pragma unroll
    for (int off = 32; off; off >>= 1) o += __shfl_xor(o, off);
    if (lane == 0) out[b] = o + ob2[0];
}

// ---------------------------------------------------------------------------
extern "C" void kernel_launch(void* const* d_in, const int* in_sizes, int n_in,
                              void* d_out, int out_size, void* d_ws, size_t ws_size,
                              hipStream_t stream)
{
    const float* rxy  = (const float*)d_in[0];
    const float* rdir = (const float*)d_in[1];
    const float* pts  = (const float*)d_in[2];
    const float* ew1  = (const float*)d_in[3];
    const float* eb1  = (const float*)d_in[4];
    const float* ew2  = (const float*)d_in[5];
    const float* eb2  = (const float*)d_in[6];
    const float* sw1  = (const float*)d_in[7];
    const float* sb1  = (const float*)d_in[8];
    const float* sw2  = (const float*)d_in[9];
    const float* sb2  = (const float*)d_in[10];
    const float* ow1  = (const float*)d_in[11];
    const float* ob1  = (const float*)d_in[12];
    const float* ow2  = (const float*)d_in[13];
    const float* ob2  = (const float*)d_in[14];
    float* out = (float*)d_out;

    const int B = in_sizes[0] / 2;
    const int N = in_sizes[2] / (2 * B);

    // workspace layout (floats): gctx[B*256] | stats[B*8] | logits[B*4*N]
    float* gctx   = (float*)d_ws;
    float* stats  = gctx + (size_t)B * 256;
    float* logits = stats + (size_t)B * 8;

    hipMemsetAsync(gctx, 0, (size_t)B * 256 * sizeof(float), stream);

    const int chunks = (N + TPB * PTS - 1) / (TPB * PTS);
    dim3 grid(chunks, B);
    k_logits<<<grid, TPB, 0, stream>>>(rxy, rdir, pts, sw1, sb1, sw2, sb2, logits, N);
    k_stats<<<dim3(B * HEADS), TPB, 0, stream>>>(logits, stats, N);
    k_ctx<<<grid, TPB, 0, stream>>>(rxy, rdir, pts, ew1, eb1, ew2, eb2, logits, stats, gctx, N);
    k_out<<<dim3(B), 64, 0, stream>>>(gctx, ow1, ob1, ow2, ob2, out);
}

// Round 2
// 159.207 us; speedup vs baseline: 7.3263x; 7.3263x over previous
//
#include <hip/hip_runtime.h>

#define HID 64
#define HEADS 4
#define TPB 256
#define PPT 8                  // register-blocked points per thread
#define BLK_PTS (TPB * PPT)    // 2048 points per block

// readlane: broadcast one lane's VGPR to SGPR (VALU pipe, avoids DS)
static __device__ __forceinline__ float rdl(float v, int l) {
    return __int_as_float(__builtin_amdgcn_readlane(__float_as_int(v), l));
}

// ---------------------------------------------------------------------------
// Fused: logits -> e=exp(lg) -> accumulate U[h][k] = sum_n e*h1[n][k], T[h] = sum_n e
// (max-subtraction and sc_b2 cancel exactly in ctx = U/T)
// ---------------------------------------------------------------------------
__global__ __launch_bounds__(TPB) void k_main(
    const float* __restrict__ rxy, const float* __restrict__ rdir,
    const float* __restrict__ pts,
    const float* __restrict__ ew1, const float* __restrict__ eb1,
    const float* __restrict__ sw1, const float* __restrict__ sb1,
    const float* __restrict__ sw2,
    float* __restrict__ Ug, float* __restrict__ Tg, int N)
{
    __shared__ float4 spack[HEADS * HID];   // {base_hd, wx, wy, w2}
    const int tid = threadIdx.x;
    const int b = blockIdx.y;
    const float rx = rxy[2 * b], ry = rxy[2 * b + 1];
    const float dx = rdir[2 * b], dy = rdir[2 * b + 1];

    {   // per-(h,d) pack: fold radar (constant per b) into the bias
        const int h = tid >> 6, d = tid & 63;
        const float* w = sw1 + (h * 6) * HID + d;
        float base = sb1[tid];
        base = fmaf(rx, w[0 * HID], base);
        base = fmaf(ry, w[1 * HID], base);
        base = fmaf(dx, w[2 * HID], base);
        base = fmaf(dy, w[3 * HID], base);
        spack[tid] = make_float4(base, w[4 * HID], w[5 * HID], sw2[tid]);
    }
    __syncthreads();

    const int lane = tid & 63;
    // encoder weights for k = lane (radar folded into baseE)
    float baseE = eb1[lane];
    baseE = fmaf(rx, ew1[0 * HID + lane], baseE);
    baseE = fmaf(ry, ew1[1 * HID + lane], baseE);
    baseE = fmaf(dx, ew1[2 * HID + lane], baseE);
    baseE = fmaf(dy, ew1[3 * HID + lane], baseE);
    const float wxE = ew1[4 * HID + lane];
    const float wyE = ew1[5 * HID + lane];

    const int wave = tid >> 6;
    const int wbase = blockIdx.x * BLK_PTS + wave * (64 * PPT);
    const float2* __restrict__ p2 = reinterpret_cast<const float2*>(pts) + (size_t)b * N;

    float px[PPT], py[PPT];
#pragma unroll
    for (int j = 0; j < PPT; ++j) {
        const int n = wbase + j * 64 + lane;
        const int nc = (n < N) ? n : (N - 1);
        const float2 p = p2[nc];
        px[j] = p.x; py[j] = p.y;
    }

    // ---------------- phase L: logits (lane = point, 8 pts register-blocked)
    float a0[PPT], a1[PPT], a2[PPT], a3[PPT];
#pragma unroll
    for (int j = 0; j < PPT; ++j) { a0[j] = 0.f; a1[j] = 0.f; a2[j] = 0.f; a3[j] = 0.f; }

#define SCORE_H(ACC, H)                                                     \
    _Pragma("unroll 4")                                                     \
    for (int d = 0; d < HID; ++d) {                                         \
        const float4 wp = spack[(H) * HID + d];                             \
        _Pragma("unroll")                                                   \
        for (int j = 0; j < PPT; ++j) {                                     \
            const float s = fmaf(py[j], wp.z, fmaf(px[j], wp.y, wp.x));     \
            ACC[j] = fmaf(fmaxf(s, 0.f), wp.w, ACC[j]);                     \
        }                                                                   \
    }
    SCORE_H(a0, 0)
    SCORE_H(a1, 1)
    SCORE_H(a2, 2)
    SCORE_H(a3, 3)
#undef SCORE_H

    // e = exp(lg) (masked), per-lane partial T
    float T0 = 0.f, T1 = 0.f, T2 = 0.f, T3 = 0.f;
#pragma unroll
    for (int j = 0; j < PPT; ++j) {
        const bool v = (wbase + j * 64 + lane) < N;
        a0[j] = v ? __expf(a0[j]) : 0.f;
        a1[j] = v ? __expf(a1[j]) : 0.f;
        a2[j] = v ? __expf(a2[j]) : 0.f;
        a3[j] = v ? __expf(a3[j]) : 0.f;
        T0 += a0[j]; T1 += a1[j]; T2 += a2[j]; T3 += a3[j];
    }

    // ---------------- phase U: lane = k, readlane-broadcast each point
    float U0 = 0.f, U1 = 0.f, U2 = 0.f, U3 = 0.f;
    for (int p = 0; p < 64; ++p) {
#pragma unroll
        for (int j = 0; j < PPT; ++j) {
            const float spx = rdl(px[j], p);
            const float spy = rdl(py[j], p);
            float hv = fmaf(spy, wyE, fmaf(spx, wxE, baseE));
            hv = fmaxf(hv, 0.f);
            U0 = fmaf(rdl(a0[j], p), hv, U0);
            U1 = fmaf(rdl(a1[j], p), hv, U1);
            U2 = fmaf(rdl(a2[j], p), hv, U2);
            U3 = fmaf(rdl(a3[j], p), hv, U3);
        }
    }

    // T: wave butterfly (24 DS ops per wave — negligible)
#pragma unroll
    for (int off = 32; off; off >>= 1) {
        T0 += __shfl_xor(T0, off);
        T1 += __shfl_xor(T1, off);
        T2 += __shfl_xor(T2, off);
        T3 += __shfl_xor(T3, off);
    }

    float* __restrict__ Ub = Ug + (size_t)b * (HEADS * HID);
    atomicAdd(&Ub[0 * HID + lane], U0);
    atomicAdd(&Ub[1 * HID + lane], U1);
    atomicAdd(&Ub[2 * HID + lane], U2);
    atomicAdd(&Ub[3 * HID + lane], U3);
    if (lane == 0) {
        float* __restrict__ Tb = Tg + (size_t)b * HEADS;
        atomicAdd(&Tb[0], T0);
        atomicAdd(&Tb[1], T1);
        atomicAdd(&Tb[2], T2);
        atomicAdd(&Tb[3], T3);
    }
}

// ---------------------------------------------------------------------------
// Finalize: ctx[h][d] = (U[h]/T_h) @ W2[:,d] + eb2[d]; then 256->64->1 MLP
// one wave per batch row; lane = d (and doubles as hidden j)
// ---------------------------------------------------------------------------
__global__ __launch_bounds__(64) void k_final(
    const float* __restrict__ Ug, const float* __restrict__ Tg,
    const float* __restrict__ ew2, const float* __restrict__ eb2,
    const float* __restrict__ ow1, const float* __restrict__ ob1,
    const float* __restrict__ ow2, const float* __restrict__ ob2,
    float* __restrict__ out)
{
    const int b = blockIdx.x;
    const int d = threadIdx.x;
    const float* __restrict__ Ub = Ug + (size_t)b * (HEADS * HID);
    const float iT0 = 1.f / Tg[b * 4 + 0];
    const float iT1 = 1.f / Tg[b * 4 + 1];
    const float iT2 = 1.f / Tg[b * 4 + 2];
    const float iT3 = 1.f / Tg[b * 4 + 3];

    float c0 = 0.f, c1 = 0.f, c2 = 0.f, c3 = 0.f;
#pragma unroll 8
    for (int k = 0; k < HID; ++k) {
        const float w2kd = ew2[k * HID + d];       // coalesced
        c0 = fmaf(Ub[0 * HID + k], w2kd, c0);      // uniform (scalar) loads
        c1 = fmaf(Ub[1 * HID + k], w2kd, c1);
        c2 = fmaf(Ub[2 * HID + k], w2kd, c2);
        c3 = fmaf(Ub[3 * HID + k], w2kd, c3);
    }
    const float e2 = eb2[d];
    const float fc0 = fmaf(c0, iT0, e2);
    const float fc1 = fmaf(c1, iT1, e2);
    const float fc2 = fmaf(c2, iT2, e2);
    const float fc3 = fmaf(c3, iT3, e2);

    float o = ob1[d];
#pragma unroll 4
    for (int k = 0; k < 64; ++k) {
        o = fmaf(rdl(fc0, k), ow1[(0 * 64 + k) * 64 + d], o);
        o = fmaf(rdl(fc1, k), ow1[(1 * 64 + k) * 64 + d], o);
        o = fmaf(rdl(fc2, k), ow1[(2 * 64 + k) * 64 + d], o);
        o = fmaf(rdl(fc3, k), ow1[(3 * 64 + k) * 64 + d], o);
    }
    o = fmaxf(o, 0.f) * ow2[d];
#pragma unroll
    for (int off = 32; off; off >>= 1) o += __shfl_xor(o, off);
    if (d == 0) out[b] = o + ob2[0];
}

// ---------------------------------------------------------------------------
extern "C" void kernel_launch(void* const* d_in, const int* in_sizes, int n_in,
                              void* d_out, int out_size, void* d_ws, size_t ws_size,
                              hipStream_t stream)
{
    const float* rxy  = (const float*)d_in[0];
    const float* rdir = (const float*)d_in[1];
    const float* pts  = (const float*)d_in[2];
    const float* ew1  = (const float*)d_in[3];
    const float* eb1  = (const float*)d_in[4];
    const float* ew2  = (const float*)d_in[5];
    const float* eb2  = (const float*)d_in[6];
    const float* sw1  = (const float*)d_in[7];
    const float* sb1  = (const float*)d_in[8];
    const float* sw2  = (const float*)d_in[9];
    // d_in[10] = sc_b2: cancels in U/T (softmax shift invariance)
    const float* ow1  = (const float*)d_in[11];
    const float* ob1  = (const float*)d_in[12];
    const float* ow2  = (const float*)d_in[13];
    const float* ob2  = (const float*)d_in[14];
    float* out = (float*)d_out;

    const int B = in_sizes[0] / 2;
    const int N = in_sizes[2] / (2 * B);

    // workspace: Ug[B*256] | Tg[B*4]  (contiguous -> one memset)
    float* Ug = (float*)d_ws;
    float* Tg = Ug + (size_t)B * (HEADS * HID);
    hipMemsetAsync(Ug, 0, (size_t)B * (HEADS * HID + HEADS) * sizeof(float), stream);

    const int chunks = (N + BLK_PTS - 1) / BLK_PTS;
    k_main<<<dim3(chunks, B), TPB, 0, stream>>>(rxy, rdir, pts, ew1, eb1,
                                                sw1, sb1, sw2, Ug, Tg, N);
    k_final<<<dim3(B), 64, 0, stream>>>(Ug, Tg, ew2, eb2, ow1, ob1, ow2, ob2, out);
}

// Round 3
// 158.093 us; speedup vs baseline: 7.3779x; 1.0070x over previous
//
#include <hip/hip_runtime.h>

#define HID 64
#define HEADS 4
#define TPB 256
#define PPT 4                  // register-blocked points per thread
#define BLK_PTS (TPB * PPT)    // 1024 points per block

// readlane: broadcast one lane's VGPR to SGPR (VALU pipe, avoids DS)
static __device__ __forceinline__ float rdl(float v, int l) {
    return __int_as_float(__builtin_amdgcn_readlane(__float_as_int(v), l));
}

// ---------------------------------------------------------------------------
// Fused: logits -> e=exp(lg) -> U[h][k] = sum_n e*h1[n][k], T[h] = sum_n e
// relu(s) = (s+|s|)/2 : linear half factorizes to 2 fma/head/pt (C_h),
// abs half is 3 VALU/(h,d,pt) with |s| as a free VOP3 modifier.
// ---------------------------------------------------------------------------
__global__ __launch_bounds__(TPB) void k_main(
    const float* __restrict__ rxy, const float* __restrict__ rdir,
    const float* __restrict__ pts,
    const float* __restrict__ ew1, const float* __restrict__ eb1,
    const float* __restrict__ sw1, const float* __restrict__ sb1,
    const float* __restrict__ sw2,
    float* __restrict__ Ug, float* __restrict__ Tg, int N)
{
    __shared__ float4 spack[HEADS * HID];   // {base_hd, wx, wy, w2/2}
    __shared__ float4 Ch[HEADS];            // {c0, c1, c2, 0} linear-part coeffs
    const int tid = threadIdx.x;
    const int b = blockIdx.y;
    const float rx = rxy[2 * b], ry = rxy[2 * b + 1];
    const float dx = rdir[2 * b], dy = rdir[2 * b + 1];

    {   // per-(h,d) pack: fold radar (constant per b) into the bias
        const int h = tid >> 6;
        const float* w = sw1 + (h * 6) * HID + (tid & 63);
        float base = sb1[tid];
        base = fmaf(rx, w[0 * HID], base);
        base = fmaf(ry, w[1 * HID], base);
        base = fmaf(dx, w[2 * HID], base);
        base = fmaf(dy, w[3 * HID], base);
        const float wx = w[4 * HID], wy = w[5 * HID];
        const float w2h = 0.5f * sw2[tid];
        spack[tid] = make_float4(base, wx, wy, w2h);
        // linear-part coefficients: reduce over d within wave (wave == head)
        float c0 = w2h * base, c1 = w2h * wx, c2 = w2h * wy;
#pragma unroll
        for (int off = 32; off; off >>= 1) {
            c0 += __shfl_xor(c0, off);
            c1 += __shfl_xor(c1, off);
            c2 += __shfl_xor(c2, off);
        }
        if ((tid & 63) == 0) Ch[h] = make_float4(c0, c1, c2, 0.f);
    }
    __syncthreads();

    const int lane = tid & 63;
    // encoder weights for k = lane (radar folded into baseE)
    float baseE = eb1[lane];
    baseE = fmaf(rx, ew1[0 * HID + lane], baseE);
    baseE = fmaf(ry, ew1[1 * HID + lane], baseE);
    baseE = fmaf(dx, ew1[2 * HID + lane], baseE);
    baseE = fmaf(dy, ew1[3 * HID + lane], baseE);
    const float wxE = ew1[4 * HID + lane];
    const float wyE = ew1[5 * HID + lane];

    const int wave = tid >> 6;
    const int wbase = blockIdx.x * BLK_PTS + wave * (64 * PPT);
    const float2* __restrict__ p2 = reinterpret_cast<const float2*>(pts) + (size_t)b * N;

    const float4 CA = Ch[0], CB = Ch[1], CC = Ch[2], CD = Ch[3];

    float px[PPT], py[PPT];
#pragma unroll
    for (int j = 0; j < PPT; ++j) {
        const int n = wbase + j * 64 + lane;
        const int nc = (n < N) ? n : (N - 1);
        const float2 p = p2[nc];
        px[j] = p.x; py[j] = p.y;
    }

    // ---------------- phase L: logits (lane = point)
    float a0[PPT], a1[PPT], a2[PPT], a3[PPT];
#pragma unroll
    for (int j = 0; j < PPT; ++j) {
        a0[j] = fmaf(py[j], CA.z, fmaf(px[j], CA.y, CA.x));
        a1[j] = fmaf(py[j], CB.z, fmaf(px[j], CB.y, CB.x));
        a2[j] = fmaf(py[j], CC.z, fmaf(px[j], CC.y, CC.x));
        a3[j] = fmaf(py[j], CD.z, fmaf(px[j], CD.y, CD.x));
    }

#define SCORE_H(ACC, H)                                                     \
    _Pragma("unroll 4")                                                     \
    for (int d = 0; d < HID; ++d) {                                         \
        const float4 wp = spack[(H) * HID + d];                             \
        _Pragma("unroll")                                                   \
        for (int j = 0; j < PPT; ++j) {                                     \
            const float s = fmaf(py[j], wp.z, fmaf(px[j], wp.y, wp.x));     \
            ACC[j] = fmaf(__builtin_fabsf(s), wp.w, ACC[j]);                \
        }                                                                   \
    }
    SCORE_H(a0, 0)
    SCORE_H(a1, 1)
    SCORE_H(a2, 2)
    SCORE_H(a3, 3)
#undef SCORE_H

    // e = exp(lg) (masked), per-lane partial T
    float T0 = 0.f, T1 = 0.f, T2 = 0.f, T3 = 0.f;
#pragma unroll
    for (int j = 0; j < PPT; ++j) {
        const bool v = (wbase + j * 64 + lane) < N;
        a0[j] = v ? __expf(a0[j]) : 0.f;
        a1[j] = v ? __expf(a1[j]) : 0.f;
        a2[j] = v ? __expf(a2[j]) : 0.f;
        a3[j] = v ? __expf(a3[j]) : 0.f;
        T0 += a0[j]; T1 += a1[j]; T2 += a2[j]; T3 += a3[j];
    }

    // ---------------- phase U: lane = k, readlane-broadcast each point
    float U0 = 0.f, U1 = 0.f, U2 = 0.f, U3 = 0.f;
    for (int p = 0; p < 64; ++p) {
#pragma unroll
        for (int j = 0; j < PPT; ++j) {
            const float spx = rdl(px[j], p);
            const float spy = rdl(py[j], p);
            float hv = fmaf(spy, wyE, fmaf(spx, wxE, baseE));
            hv = fmaxf(hv, 0.f);
            U0 = fmaf(rdl(a0[j], p), hv, U0);
            U1 = fmaf(rdl(a1[j], p), hv, U1);
            U2 = fmaf(rdl(a2[j], p), hv, U2);
            U3 = fmaf(rdl(a3[j], p), hv, U3);
        }
    }

    // T: wave butterfly (24 DS ops per wave — negligible)
#pragma unroll
    for (int off = 32; off; off >>= 1) {
        T0 += __shfl_xor(T0, off);
        T1 += __shfl_xor(T1, off);
        T2 += __shfl_xor(T2, off);
        T3 += __shfl_xor(T3, off);
    }

    float* __restrict__ Ub = Ug + (size_t)b * (HEADS * HID);
    atomicAdd(&Ub[0 * HID + lane], U0);
    atomicAdd(&Ub[1 * HID + lane], U1);
    atomicAdd(&Ub[2 * HID + lane], U2);
    atomicAdd(&Ub[3 * HID + lane], U3);
    if (lane == 0) {
        float* __restrict__ Tb = Tg + (size_t)b * HEADS;
        atomicAdd(&Tb[0], T0);
        atomicAdd(&Tb[1], T1);
        atomicAdd(&Tb[2], T2);
        atomicAdd(&Tb[3], T3);
    }
}

// ---------------------------------------------------------------------------
// Finalize: ctx[h][d] = (U[h]/T_h) @ W2[:,d] + eb2[d]; then 256->64->1 MLP
// 256 threads per batch row: wave = h for ctx, wave = k-quarter for the MLP.
// ---------------------------------------------------------------------------
__global__ __launch_bounds__(256) void k_final(
    const float* __restrict__ Ug, const float* __restrict__ Tg,
    const float* __restrict__ ew2, const float* __restrict__ eb2,
    const float* __restrict__ ow1, const float* __restrict__ ob1,
    const float* __restrict__ ow2, const float* __restrict__ ob2,
    float* __restrict__ out)
{
    const int b = blockIdx.x;
    const int t = threadIdx.x;
    const int h = t >> 6, d = t & 63;
    __shared__ float fcs[HEADS * HID];
    __shared__ float partials[256];

    const float* __restrict__ Ub = Ug + (size_t)b * (HEADS * HID) + h * HID;
    const float iT = 1.f / Tg[b * HEADS + h];
    float acc = 0.f;
#pragma unroll 8
    for (int k = 0; k < HID; ++k)
        acc = fmaf(Ub[k], ew2[k * HID + d], acc);   // Ub[k] wave-uniform
    fcs[t] = fmaf(acc, iT, eb2[d]);
    __syncthreads();

    // o[d] = relu(fc @ ow1 + ob1)[d]; split K=256 across the 4 waves
    float part = (h == 0) ? ob1[d] : 0.f;
    const float* __restrict__ fq = fcs + h * HID;
#pragma unroll 8
    for (int k = 0; k < HID; ++k)
        part = fmaf(fq[k], ow1[(h * HID + k) * 64 + d], part);
    partials[t] = part;
    __syncthreads();

    if (t < 64) {
        float o = partials[t] + partials[t + 64] + partials[t + 128] + partials[t + 192];
        o = fmaxf(o, 0.f) * ow2[t];
#pragma unroll
        for (int off = 32; off; off >>= 1) o += __shfl_xor(o, off);
        if (t == 0) out[b] = o + ob2[0];
    }
}

// ---------------------------------------------------------------------------
extern "C" void kernel_launch(void* const* d_in, const int* in_sizes, int n_in,
                              void* d_out, int out_size, void* d_ws, size_t ws_size,
                              hipStream_t stream)
{
    const float* rxy  = (const float*)d_in[0];
    const float* rdir = (const float*)d_in[1];
    const float* pts  = (const float*)d_in[2];
    const float* ew1  = (const float*)d_in[3];
    const float* eb1  = (const float*)d_in[4];
    const float* ew2  = (const float*)d_in[5];
    const float* eb2  = (const float*)d_in[6];
    const float* sw1  = (const float*)d_in[7];
    const float* sb1  = (const float*)d_in[8];
    const float* sw2  = (const float*)d_in[9];
    // d_in[10] = sc_b2: cancels in U/T (softmax shift invariance)
    const float* ow1  = (const float*)d_in[11];
    const float* ob1  = (const float*)d_in[12];
    const float* ow2  = (const float*)d_in[13];
    const float* ob2  = (const float*)d_in[14];
    float* out = (float*)d_out;

    const int B = in_sizes[0] / 2;
    const int N = in_sizes[2] / (2 * B);

    // workspace: Ug[B*256] | Tg[B*4]  (contiguous -> one memset)
    float* Ug = (float*)d_ws;
    float* Tg = Ug + (size_t)B * (HEADS * HID);
    hipMemsetAsync(Ug, 0, (size_t)B * (HEADS * HID + HEADS) * sizeof(float), stream);

    const int chunks = (N + BLK_PTS - 1) / BLK_PTS;
    k_main<<<dim3(chunks, B), TPB, 0, stream>>>(rxy, rdir, pts, ew1, eb1,
                                                sw1, sb1, sw2, Ug, Tg, N);
    k_final<<<dim3(B), 256, 0, stream>>>(Ug, Tg, ew2, eb2, ow1, ob1, ow2, ob2, out);
}